// Round 5
// baseline (428.616 us; speedup 1.0000x reference)
//
#include <hip/hip_runtime.h>
#include <hip/hip_fp16.h>

#define N_NODES 100000
#define PAD_N   100096                   // 782 * 128, padded M for GEMM tiles
#define IN_DIM 128
#define HID 128
#define N_REL 2
#define N_EDGES 500000
#define M_SEG (N_REL * N_NODES)          // 200000 (rel,node) segments
#define SCAN_BLK 1024
#define SCAN_NB ((M_SEG + SCAN_BLK - 1) / SCAN_BLK)   // 196
#define N_TILES (PAD_N / 16)             // 6256 16-row tiles
#define GEMM_BLOCKS 256                  // persistent, 1 block/CU (96 KB LDS)

#define CVT_BLOCKS 12500                 // N_NODES*IN_DIM/4 / 256
#define PACK_BLOCKS 48                   // 2*12*8*64 / 256
#define HIST_BLOCKS 1954                 // ceil(N_EDGES/256)

typedef __attribute__((ext_vector_type(8))) _Float16 half8;
typedef __attribute__((ext_vector_type(4))) float float4v;

__device__ __forceinline__ unsigned short f2h(float f) {
    return __half_as_ushort(__float2half(f));   // RNE
}

// ---------------------------------------------------------------------------
// Fused prep: cvt (x fp32->fp16) | pack (weights->B-frag order, fp16) | hist.
// ---------------------------------------------------------------------------
__global__ __launch_bounds__(256) void prep_kernel(
    const float* __restrict__ X, unsigned short* __restrict__ Xb,
    const float* __restrict__ Wroot1, const float* __restrict__ Wrel1,
    const float* __restrict__ Wroot2, const float* __restrict__ Wrel2,
    unsigned short* __restrict__ Wp,
    const int* __restrict__ ei, const int* __restrict__ et,
    unsigned* __restrict__ cnt)
{
    int bid = blockIdx.x;
    if (bid < CVT_BLOCKS) {
        int i = bid * 256 + threadIdx.x;
        if (i >= N_NODES * IN_DIM / 4) return;
        float4 v = ((const float4*)X)[i];
        ushort4 o;
        o.x = f2h(v.x); o.y = f2h(v.y); o.z = f2h(v.z); o.w = f2h(v.w);
        ((ushort4*)Xb)[i] = o;
    } else if (bid < CVT_BLOCKS + PACK_BLOCKS) {
        int tid = (bid - CVT_BLOCKS) * 256 + threadIdx.x;
        int layer = tid / 6144;
        int rem   = tid % 6144;
        int ks    = rem / 512;
        int rem2  = rem % 512;
        int nt    = rem2 / 64;
        int lane  = rem2 % 64;
        int seg = ks >> 2;
        int kl  = (ks & 3) * 32 + (lane >> 4) * 8;
        int chan = nt * 16 + (lane & 15);
        const float* Wroot = layer ? Wroot2 : Wroot1;
        const float* Wrel  = layer ? Wrel2  : Wrel1;
        const float* W = (seg == 0) ? Wroot : (Wrel + (size_t)(seg - 1) * 128 * 128);
        unsigned short* dst = Wp + (size_t)tid * 8;
        #pragma unroll
        for (int j = 0; j < 8; ++j)
            dst[j] = f2h(W[(size_t)(kl + j) * 128 + chan]);
    } else {
        int e = (bid - CVT_BLOCKS - PACK_BLOCKS) * 256 + threadIdx.x;
        if (e >= N_EDGES) return;
        int dst = ei[N_EDGES + e];
        int r = et[e];
        atomicAdd(cnt + (size_t)r * N_NODES + dst, 1u);
    }
}

// ---------------------------------------------------------------------------
// Scan chain for CSR row starts (scan1 -> scan3; scan2 folded into scan3)
// ---------------------------------------------------------------------------
__global__ __launch_bounds__(256) void scan1_kernel(
    const unsigned* __restrict__ cnt,
    unsigned* __restrict__ rs, unsigned* __restrict__ bsums)
{
    __shared__ unsigned sdata[256];
    int t = threadIdx.x;
    int base = blockIdx.x * SCAN_BLK + t * 4;
    unsigned v[4]; unsigned s = 0;
    #pragma unroll
    for (int j = 0; j < 4; ++j) {
        v[j] = (base + j < M_SEG) ? cnt[base + j] : 0u;
        s += v[j];
    }
    sdata[t] = s;
    __syncthreads();
    #pragma unroll
    for (int off = 1; off < 256; off <<= 1) {
        unsigned x = (t >= off) ? sdata[t - off] : 0u;
        __syncthreads();
        if (t >= off) sdata[t] += x;
        __syncthreads();
    }
    unsigned excl = (t > 0) ? sdata[t - 1] : 0u;
    if (t == 255) bsums[blockIdx.x] = sdata[255];
    unsigned run = excl;
    #pragma unroll
    for (int j = 0; j < 4; ++j) {
        if (base + j < M_SEG) rs[base + j] = run;
        run += v[j];
    }
}

// scan3: each block redundantly scans the 196 block sums in LDS (trivial),
// then applies the offset.  Removes the serial single-block scan2 dispatch.
__global__ __launch_bounds__(256) void scan3_kernel(
    unsigned* __restrict__ rs, const unsigned* __restrict__ bsums,
    unsigned* __restrict__ cursor)
{
    __shared__ unsigned sdata[256];
    int t = threadIdx.x;
    sdata[t] = (t < SCAN_NB) ? bsums[t] : 0u;
    __syncthreads();
    #pragma unroll
    for (int off = 1; off < 256; off <<= 1) {
        unsigned x = (t >= off) ? sdata[t - off] : 0u;
        __syncthreads();
        if (t >= off) sdata[t] += x;
        __syncthreads();
    }
    int i = blockIdx.x * blockDim.x + t;
    if (i < M_SEG) {
        int b = i >> 10;
        unsigned add = (b > 0) ? sdata[b - 1] : 0u;
        unsigned v = rs[i] + add;
        rs[i] = v;
        cursor[i] = v;
    }
    if (i == 0) rs[M_SEG] = N_EDGES;
}

__global__ __launch_bounds__(256) void fill_kernel(
    const int* __restrict__ ei, const int* __restrict__ et,
    unsigned* __restrict__ cursor, unsigned* __restrict__ csr)
{
    int e = blockIdx.x * blockDim.x + threadIdx.x;
    if (e >= N_EDGES) return;
    int src = ei[e];
    int dst = ei[N_EDGES + e];
    int r = et[e];
    unsigned pos = atomicAdd(cursor + (size_t)r * N_NODES + dst, 1u);
    csr[pos] = (unsigned)src;
}

// ---------------------------------------------------------------------------
// Persistent fused gather + MFMA GEMM (fp16):
//  * 256 blocks x 1024 threads (16 waves), 96 KB LDS -> exactly 1 block/CU,
//    4 waves/SIMD fixed by geometry (no launch-bounds reg squeeze -> no spill).
//  * All of B (12 ks x 8 nt x 1 KB = 96 KB) staged to LDS ONCE per block via
//    global_load_lds; ONE barrier total; B then fed by pipelined ds_read_b128
//    -> removes the per-wave 12-round serial global B chain and ~600 MB of
//    L2 traffic per dispatch.
//  * Waves pull 16-row tiles from a global atomic ticket: degree imbalance
//    self-balances, no per-block dispatch drain.
//  * Gather: per-lane CSR walk, 2 edge-slots per relation, IDs software-
//    pipelined, predicated v_pk_fma_f16 accumulation (round-3 body).
// ---------------------------------------------------------------------------
template <bool FINAL>
__global__ __launch_bounds__(1024) void gemm_kernel(
    const unsigned short* __restrict__ Xin,   // [PAD_N][128] fp16 (layer input + gather source)
    const unsigned* __restrict__ rs,          // [M_SEG+1] CSR row starts
    const unsigned* __restrict__ csr,         // [N_EDGES] src node per slot
    const unsigned short* __restrict__ Wp,    // packed [12][8][64][8] fp16
    const float* __restrict__ bias,           // [128] fp32
    unsigned* __restrict__ tick,              // work ticket (init 0)
    unsigned short* __restrict__ Hout,        // [PAD_N][128] fp16 (!FINAL)
    const float* __restrict__ Wc,             // [128][2] fp32 (FINAL)
    const float* __restrict__ bc,             // [2] fp32 (FINAL)
    float* __restrict__ Out)                  // [N][2] fp32 (FINAL)
{
    __shared__ unsigned short ldsB[12 * 8 * 512];   // 96 KB

    const int t    = threadIdx.x;
    const int w    = t >> 6;          // wave 0..15
    const int lane = t & 63;
    const int l15  = lane & 15;
    const int quad = lane >> 4;
    const int koff = quad * 8;

    // ---- stage all of B into LDS (wave w stages frags 6w..6w+5) ----
    #pragma unroll
    for (int fi = 0; fi < 6; ++fi) {
        int f = w * 6 + fi;               // 0..95 = ks*8+nt
        const unsigned short* g = Wp + ((size_t)f * 64 + lane) * 8;
        unsigned short* l = &ldsB[(size_t)f * 512];
        __builtin_amdgcn_global_load_lds(
            (const __attribute__((address_space(1))) unsigned int*)g,
            (__attribute__((address_space(3))) unsigned int*)l, 16, 0, 0);
    }
    __syncthreads();                      // only barrier in the kernel

    // hoisted per-lane constants
    float bv[8];
    #pragma unroll
    for (int nt = 0; nt < 8; ++nt) bv[nt] = bias[nt * 16 + l15];
    float wc0[8], wc1[8], b0 = 0.f, b1 = 0.f;
    if (FINAL) {
        #pragma unroll
        for (int nt = 0; nt < 8; ++nt) {
            wc0[nt] = Wc[(nt * 16 + l15) * 2 + 0];
            wc1[nt] = Wc[(nt * 16 + l15) * 2 + 1];
        }
        b0 = bc[0]; b1 = bc[1];
    }

    const uint4* __restrict__ X4 = (const uint4*)Xin;   // 16B units
    const __half2 one2  = __float2half2_rn(1.f);
    const __half2 zero2 = __float2half2_rn(0.f);

    while (true) {
        // ---- per-wave tile ticket ----
        unsigned tk = 0;
        if (lane == 0) tk = atomicAdd(tick, 1u);
        tk = (unsigned)__shfl((int)tk, 0);
        if (tk >= (unsigned)N_TILES) break;
        const int rowbase = (int)tk * 16;
        const int node = rowbase + l15;

        // seg-0 A-frags: issue early (own row, contiguous)
        const unsigned short* aBase = Xin + (size_t)node * 128 + koff;
        half8 ax[4];
        #pragma unroll
        for (int ksl = 0; ksl < 4; ++ksl)
            ax[ksl] = *(const half8*)(aBase + ksl * 32);

        // ---- segment bounds for the 2 relation walks of this lane's node ----
        unsigned p_[2], e_[2]; float inv_[2];
        #pragma unroll
        for (int r = 0; r < 2; ++r) {
            unsigned st = 0, en = 0;
            if (node < N_NODES) {
                unsigned sg = (unsigned)r * N_NODES + (unsigned)node;
                st = rs[sg];
                en = rs[sg + 1];
            }
            p_[r] = st; e_[r] = en;
            unsigned d = en - st;
            inv_[r] = 1.0f / (float)(d ? d : 1u);
        }

        __half2 a2[2][4][4];              // [r][ksl][j] — statically indexed
        #pragma unroll
        for (int r = 0; r < 2; ++r)
            #pragma unroll
            for (int ksl = 0; ksl < 4; ++ksl)
                #pragma unroll
                for (int j = 0; j < 4; ++j)
                    a2[r][ksl][j] = __float2half2_rn(0.f);

        // prolog: IDs for the first 2 edge-slots of each walk
        unsigned id[2][2];
        #pragma unroll
        for (int r = 0; r < 2; ++r)
            #pragma unroll
            for (int s = 0; s < 2; ++s) {
                unsigned q = p_[r] + (unsigned)s;
                id[r][s] = csr[q < e_[r] ? q : 0u];
            }

        while (__any((p_[0] < e_[0]) | (p_[1] < e_[1]))) {
            bool act[2][2];
            #pragma unroll
            for (int r = 0; r < 2; ++r)
                #pragma unroll
                for (int s = 0; s < 2; ++s)
                    act[r][s] = (p_[r] + (unsigned)s) < e_[r];

            // 16 independent 16B row loads for the current IDs
            uint4 v[2][2][4];
            #pragma unroll
            for (int r = 0; r < 2; ++r)
                #pragma unroll
                for (int s = 0; s < 2; ++s) {
                    const uint4* row = X4 +
                        ((size_t)(act[r][s] ? id[r][s] : 0u) << 4) + quad;
                    v[r][s][0] = row[0];
                    v[r][s][1] = row[4];
                    v[r][s][2] = row[8];
                    v[r][s][3] = row[12];
                }

            // advance pointers and prefetch NEXT iteration's IDs
            unsigned pn[2];
            #pragma unroll
            for (int r = 0; r < 2; ++r) {
                unsigned q = p_[r] + 2u;
                pn[r] = q > e_[r] ? e_[r] : q;
            }
            unsigned idn[2][2];
            #pragma unroll
            for (int r = 0; r < 2; ++r)
                #pragma unroll
                for (int s = 0; s < 2; ++s) {
                    unsigned q = pn[r] + (unsigned)s;
                    idn[r][s] = csr[q < e_[r] ? q : 0u];
                }

            // predicated packed-fma accumulate (slot order preserves edge order)
            #pragma unroll
            for (int r = 0; r < 2; ++r)
                #pragma unroll
                for (int s = 0; s < 2; ++s) {
                    __half2 m = act[r][s] ? one2 : zero2;
                    #pragma unroll
                    for (int ksl = 0; ksl < 4; ++ksl)
                        #pragma unroll
                        for (int j = 0; j < 4; ++j)
                            a2[r][ksl][j] = __hfma2(((const __half2*)&v[r][s][ksl])[j],
                                                    m, a2[r][ksl][j]);
                }

            #pragma unroll
            for (int r = 0; r < 2; ++r) {
                p_[r] = pn[r];
                #pragma unroll
                for (int s = 0; s < 2; ++s) id[r][s] = idn[r][s];
            }
        }

        // scale to means
        half8 ag[2][4];                   // [r][ksl]
        #pragma unroll
        for (int r = 0; r < 2; ++r) {
            __half2 s2 = __float2half2_rn(inv_[r]);
            #pragma unroll
            for (int ksl = 0; ksl < 4; ++ksl) {
                half8 h;
                #pragma unroll
                for (int j = 0; j < 4; ++j)
                    ((__half2*)&h)[j] = __hmul2(a2[r][ksl][j], s2);
                ag[r][ksl] = h;
            }
        }

        // ---- MFMA phase: B from LDS (pipelined ds_read_b128) ----
        float4v acc[8];
        #pragma unroll
        for (int nt = 0; nt < 8; ++nt)
            acc[nt] = float4v{bv[nt], bv[nt], bv[nt], bv[nt]};

        #pragma unroll
        for (int ks = 0; ks < 12; ++ks) {
            half8 b[8];
            #pragma unroll
            for (int nt = 0; nt < 8; ++nt)
                b[nt] = *(const half8*)(&ldsB[(size_t)(ks * 8 + nt) * 512] + lane * 8);
            half8 A = (ks < 4) ? ax[ks & 3] : ag[(ks >> 2) - 1][ks & 3];
            #pragma unroll
            for (int nt = 0; nt < 8; ++nt)
                acc[nt] = __builtin_amdgcn_mfma_f32_16x16x32_f16(A, b[nt], acc[nt], 0, 0, 0);
        }

        if (!FINAL) {
            // D layout: row = quad*4 + rr, col = l15 (within each 16x16 tile)
            #pragma unroll
            for (int rr = 0; rr < 4; ++rr) {
                int n2 = rowbase + quad * 4 + rr;
                unsigned short* hp = Hout + (size_t)n2 * 128 + l15;
                #pragma unroll
                for (int nt = 0; nt < 8; ++nt)
                    hp[nt * 16] = f2h(fmaxf(acc[nt][rr], 0.f));
            }
        } else {
            #pragma unroll
            for (int rr = 0; rr < 4; ++rr) {
                float l0 = 0.f, l1 = 0.f;
                #pragma unroll
                for (int nt = 0; nt < 8; ++nt) {
                    float h = fmaxf(acc[nt][rr], 0.f);
                    l0 += h * wc0[nt];
                    l1 += h * wc1[nt];
                }
                #pragma unroll
                for (int off = 8; off > 0; off >>= 1) {
                    l0 += __shfl_down(l0, off, 16);
                    l1 += __shfl_down(l1, off, 16);
                }
                int n2 = rowbase + quad * 4 + rr;
                if (l15 == 0 && n2 < N_NODES) {
                    Out[(size_t)n2 * 2 + 0] = l0 + b0;
                    Out[(size_t)n2 * 2 + 1] = l1 + b1;
                }
            }
        }
    }
}

extern "C" void kernel_launch(void* const* d_in, const int* in_sizes, int n_in,
                              void* d_out, int out_size, void* d_ws, size_t ws_size,
                              hipStream_t stream)
{
    const float* x      = (const float*)d_in[0];
    const int*   ei     = (const int*)d_in[1];
    const int*   et     = (const int*)d_in[2];
    const float* Wrel1  = (const float*)d_in[3];
    const float* Wroot1 = (const float*)d_in[4];
    const float* b1     = (const float*)d_in[5];
    const float* Wrel2  = (const float*)d_in[6];
    const float* Wroot2 = (const float*)d_in[7];
    const float* b2     = (const float*)d_in[8];
    const float* Wc     = (const float*)d_in[9];
    const float* bc     = (const float*)d_in[10];
    float* out = (float*)d_out;

    char* ws = (char*)d_ws;
    size_t off = 0;
    auto alloc = [&](size_t bytes) {
        void* p = ws + off;
        off += (bytes + 255) & ~(size_t)255;
        return p;
    };
    unsigned short* xb    = (unsigned short*)alloc((size_t)PAD_N * IN_DIM * 2);
    unsigned short* h1b   = (unsigned short*)alloc((size_t)PAD_N * HID * 2);
    unsigned short* Wp    = (unsigned short*)alloc((size_t)2 * 12 * 8 * 64 * 8 * 2);
    unsigned*       rs    = (unsigned*)alloc((size_t)(M_SEG + 1) * 4);
    unsigned*       cursor= (unsigned*)alloc((size_t)M_SEG * 4);
    unsigned*       bsums = (unsigned*)alloc(256 * 4);
    unsigned*       csr   = (unsigned*)alloc((size_t)N_EDGES * 4);
    unsigned*       tick  = (unsigned*)alloc(256);

    const int edge_blocks = (N_EDGES + 255) / 256;
    const int seg_blocks  = (M_SEG + 255) / 256;
    const int prep_blocks = CVT_BLOCKS + PACK_BLOCKS + HIST_BLOCKS;

    // ---- CSR build + conversions (graph identical for both layers) ----
    hipMemsetAsync(cursor, 0, (size_t)M_SEG * 4, stream);
    hipMemsetAsync(tick, 0, 8, stream);
    prep_kernel<<<prep_blocks, 256, 0, stream>>>(
        x, xb, Wroot1, Wrel1, Wroot2, Wrel2, Wp, ei, et, cursor);
    scan1_kernel<<<SCAN_NB, 256, 0, stream>>>(cursor, rs, bsums);
    scan3_kernel<<<seg_blocks, 256, 0, stream>>>(rs, bsums, cursor);
    fill_kernel<<<edge_blocks, 256, 0, stream>>>(ei, et, cursor, csr);

    // ---- layer 1 (persistent fused gather+gemm) ----
    gemm_kernel<false><<<GEMM_BLOCKS, 1024, 0, stream>>>(
        xb, rs, csr, Wp, b1, tick + 0, h1b, nullptr, nullptr, nullptr);

    // ---- layer 2 (persistent fused gather+gemm, FINAL classifier) ----
    gemm_kernel<true><<<GEMM_BLOCKS, 1024, 0, stream>>>(
        h1b, rs, csr, Wp + (size_t)12 * 8 * 64 * 8, b2, tick + 1, nullptr, Wc, bc, out);
}

// Round 6
// 332.477 us; speedup vs baseline: 1.2892x; 1.2892x over previous
//
#include <hip/hip_runtime.h>
#include <hip/hip_fp16.h>

#define N_NODES 100000
#define PAD_N   100096                   // 782 * 128, padded M for GEMM tiles
#define IN_DIM 128
#define HID 128
#define N_REL 2
#define N_EDGES 500000
#define M_SEG (N_REL * N_NODES)          // 200000 (rel,node) segments
#define SCAN_BLK 1024
#define CSR_NB ((M_SEG + SCAN_BLK - 1) / SCAN_BLK)   // 196 blocks, co-resident

#define CVT_BLOCKS 12500                 // N_NODES*IN_DIM/4 / 256
#define PACK_BLOCKS 48                   // 2*12*8*64 / 256
#define HIST_BLOCKS 1954                 // ceil(N_EDGES/256)

typedef __attribute__((ext_vector_type(8))) _Float16 half8;
typedef __attribute__((ext_vector_type(4))) float float4v;

__device__ __forceinline__ unsigned short f2h(float f) {
    return __half_as_ushort(__float2half(f));   // RNE
}

// ---------------------------------------------------------------------------
// Fused prep: cvt (x fp32->fp16) | pack (weights->B-frag order, fp16) | hist.
// ---------------------------------------------------------------------------
__global__ __launch_bounds__(256) void prep_kernel(
    const float* __restrict__ X, unsigned short* __restrict__ Xb,
    const float* __restrict__ Wroot1, const float* __restrict__ Wrel1,
    const float* __restrict__ Wroot2, const float* __restrict__ Wrel2,
    unsigned short* __restrict__ Wp,
    const int* __restrict__ ei, const int* __restrict__ et,
    unsigned* __restrict__ cnt)
{
    int bid = blockIdx.x;
    if (bid < CVT_BLOCKS) {
        int i = bid * 256 + threadIdx.x;
        if (i >= N_NODES * IN_DIM / 4) return;
        float4 v = ((const float4*)X)[i];
        ushort4 o;
        o.x = f2h(v.x); o.y = f2h(v.y); o.z = f2h(v.z); o.w = f2h(v.w);
        ((ushort4*)Xb)[i] = o;
    } else if (bid < CVT_BLOCKS + PACK_BLOCKS) {
        int tid = (bid - CVT_BLOCKS) * 256 + threadIdx.x;
        int layer = tid / 6144;
        int rem   = tid % 6144;
        int ks    = rem / 512;
        int rem2  = rem % 512;
        int nt    = rem2 / 64;
        int lane  = rem2 % 64;
        int seg = ks >> 2;
        int kl  = (ks & 3) * 32 + (lane >> 4) * 8;
        int chan = nt * 16 + (lane & 15);
        const float* Wroot = layer ? Wroot2 : Wroot1;
        const float* Wrel  = layer ? Wrel2  : Wrel1;
        const float* W = (seg == 0) ? Wroot : (Wrel + (size_t)(seg - 1) * 128 * 128);
        unsigned short* dst = Wp + (size_t)tid * 8;
        #pragma unroll
        for (int j = 0; j < 8; ++j)
            dst[j] = f2h(W[(size_t)(kl + j) * 128 + chan]);
    } else {
        int e = (bid - CVT_BLOCKS - PACK_BLOCKS) * 256 + threadIdx.x;
        if (e >= N_EDGES) return;
        int dst = ei[N_EDGES + e];
        int r = et[e];
        atomicAdd(cnt + (size_t)r * N_NODES + dst, 1u);
    }
}

// ---------------------------------------------------------------------------
// csr_kernel: scan1 + scan3 + fill fused into ONE dispatch.
// 196 blocks (<= 1/CU, guaranteed co-resident) with two software device
// barriers (device-scope atomic counter + threadfence, per XCD-coherence
// rules).  Phase 1: per-block chunk sums -> bsums.  Phase 2: every block
// scans the 196 bsums in LDS, writes rs + cursor for its chunk.  Phase 3:
// grid-stride edge fill via atomic cursors.
// ---------------------------------------------------------------------------
__global__ __launch_bounds__(256) void csr_kernel(
    const int* __restrict__ ei, const int* __restrict__ et,
    unsigned* __restrict__ cursor,   // in: per-seg degree counts; out: cursors
    unsigned* __restrict__ rs,
    unsigned* __restrict__ bsums,
    unsigned* __restrict__ done,     // zeroed each launch
    unsigned* __restrict__ csr)
{
    __shared__ unsigned sdata[256];
    __shared__ unsigned sb[256];
    const int b = blockIdx.x, t = threadIdx.x;
    const int base = b * SCAN_BLK + t * 4;

    // ---- phase 1: local values + block-inclusive scan ----
    unsigned v[4]; unsigned s = 0;
    #pragma unroll
    for (int j = 0; j < 4; ++j) {
        v[j] = (base + j < M_SEG) ? cursor[base + j] : 0u;
        s += v[j];
    }
    sdata[t] = s;
    __syncthreads();
    #pragma unroll
    for (int off = 1; off < 256; off <<= 1) {
        unsigned x = (t >= off) ? sdata[t - off] : 0u;
        __syncthreads();
        if (t >= off) sdata[t] += x;
        __syncthreads();
    }
    if (t == 255) {
        bsums[b] = sdata[255];
        __threadfence();
        atomicAdd(done, 1u);
    }
    if (t == 0) { while (atomicAdd(done, 0u) < (unsigned)CSR_NB) {} }
    __syncthreads();
    __threadfence();   // acquire: bsums of all blocks now visible

    // ---- phase 2: scan bsums, write rs + cursor ----
    sb[t] = (t < CSR_NB) ? bsums[t] : 0u;
    __syncthreads();
    #pragma unroll
    for (int off = 1; off < 256; off <<= 1) {
        unsigned x = (t >= off) ? sb[t - off] : 0u;
        __syncthreads();
        if (t >= off) sb[t] += x;
        __syncthreads();
    }
    unsigned goff = (b > 0) ? sb[b - 1] : 0u;
    unsigned excl = (t > 0) ? sdata[t - 1] : 0u;
    unsigned run = goff + excl;
    #pragma unroll
    for (int j = 0; j < 4; ++j) {
        if (base + j < M_SEG) { rs[base + j] = run; cursor[base + j] = run; }
        run += v[j];
    }
    if (b == 0 && t == 0) rs[M_SEG] = N_EDGES;

    // ---- barrier 2: rs/cursor visible everywhere before fill ----
    __threadfence();
    __syncthreads();
    if (t == 0) {
        atomicAdd(done, 1u);
        while (atomicAdd(done, 0u) < 2u * (unsigned)CSR_NB) {}
    }
    __syncthreads();
    __threadfence();

    // ---- phase 3: fill (grid-stride over edges) ----
    for (int e = b * 256 + t; e < N_EDGES; e += CSR_NB * 256) {
        int src = ei[e];
        int dst = ei[N_EDGES + e];
        int r = et[e];
        unsigned pos = atomicAdd(cursor + (size_t)r * N_NODES + dst, 1u);
        csr[pos] = (unsigned)src;
    }
}

// ---------------------------------------------------------------------------
// Fused gather + MFMA GEMM (fp16) — round-3 configuration (best verified):
//  * 256 threads, DEFAULT launch bounds (84 VGPR, no spill — forced bounds
//    spilled in rounds 4/5).
//  * wave owns 16 rows; gather: 2 relation walks x 2 edge-slots, CSR IDs
//    software-pipelined, predicated v_pk_fma_f16 accumulation.
//  * No LDS, no __syncthreads; B read from L2 with depth-2 ping-pong.
// ---------------------------------------------------------------------------
template <bool FINAL>
__global__ __launch_bounds__(256) void gemm_kernel(
    const unsigned short* __restrict__ Xin,   // [PAD_N][128] fp16 (layer input + gather source)
    const unsigned* __restrict__ rs,          // [M_SEG+1] CSR row starts
    const unsigned* __restrict__ csr,         // [N_EDGES] src node per slot
    const unsigned short* __restrict__ Wp,    // packed [12][8][64][8] fp16
    const float* __restrict__ bias,           // [128] fp32
    unsigned short* __restrict__ Hout,        // [PAD_N][128] fp16 (!FINAL)
    const float* __restrict__ Wc,             // [128][2] fp32 (FINAL)
    const float* __restrict__ bc,             // [2] fp32 (FINAL)
    float* __restrict__ Out)                  // [N][2] fp32 (FINAL)
{
    const int t    = threadIdx.x;
    const int w    = t >> 6;          // wave 0..3
    const int lane = t & 63;
    const int l15  = lane & 15;
    const int quad = lane >> 4;
    const int rowbase = blockIdx.x * 64 + w * 16;   // this wave's 16 nodes
    const int koff = quad * 8;

    const uint4* __restrict__ X4 = (const uint4*)Xin;   // 16B units

    // ---- segment bounds for the 2 relation walks of this lane's node ----
    const int node = rowbase + l15;
    unsigned p_[2], e_[2]; float inv_[2];
    #pragma unroll
    for (int r = 0; r < 2; ++r) {
        unsigned st = 0, en = 0;
        if (node < N_NODES) {
            unsigned sg = (unsigned)r * N_NODES + (unsigned)node;
            st = rs[sg];
            en = rs[sg + 1];
        }
        p_[r] = st; e_[r] = en;
        unsigned d = en - st;
        inv_[r] = 1.0f / (float)(d ? d : 1u);
    }

    __half2 a2[2][4][4];              // [r][ksl][j] — statically indexed
    #pragma unroll
    for (int r = 0; r < 2; ++r)
        #pragma unroll
        for (int ksl = 0; ksl < 4; ++ksl)
            #pragma unroll
            for (int j = 0; j < 4; ++j)
                a2[r][ksl][j] = __float2half2_rn(0.f);

    const __half2 one2  = __float2half2_rn(1.f);
    const __half2 zero2 = __float2half2_rn(0.f);

    // prolog: IDs for the first 2 edge-slots of each walk
    unsigned id[2][2];
    #pragma unroll
    for (int r = 0; r < 2; ++r)
        #pragma unroll
        for (int s = 0; s < 2; ++s) {
            unsigned q = p_[r] + (unsigned)s;
            id[r][s] = csr[q < e_[r] ? q : 0u];
        }

    while (__any((p_[0] < e_[0]) | (p_[1] < e_[1]))) {
        // activity of the current 4 edge-slots (from p_, no loads)
        bool act[2][2];
        #pragma unroll
        for (int r = 0; r < 2; ++r)
            #pragma unroll
            for (int s = 0; s < 2; ++s)
                act[r][s] = (p_[r] + (unsigned)s) < e_[r];

        // 16 independent 16B row loads for the current IDs
        uint4 v[2][2][4];
        #pragma unroll
        for (int r = 0; r < 2; ++r)
            #pragma unroll
            for (int s = 0; s < 2; ++s) {
                const uint4* row = X4 +
                    ((size_t)(act[r][s] ? id[r][s] : 0u) << 4) + quad;
                v[r][s][0] = row[0];
                v[r][s][1] = row[4];
                v[r][s][2] = row[8];
                v[r][s][3] = row[12];
            }

        // advance pointers and prefetch NEXT iteration's IDs (independent of v)
        unsigned pn[2];
        #pragma unroll
        for (int r = 0; r < 2; ++r) {
            unsigned q = p_[r] + 2u;
            pn[r] = q > e_[r] ? e_[r] : q;
        }
        unsigned idn[2][2];
        #pragma unroll
        for (int r = 0; r < 2; ++r)
            #pragma unroll
            for (int s = 0; s < 2; ++s) {
                unsigned q = pn[r] + (unsigned)s;
                idn[r][s] = csr[q < e_[r] ? q : 0u];
            }

        // predicated packed-fma accumulate (slot order preserves edge order)
        #pragma unroll
        for (int r = 0; r < 2; ++r)
            #pragma unroll
            for (int s = 0; s < 2; ++s) {
                __half2 m = act[r][s] ? one2 : zero2;
                #pragma unroll
                for (int ksl = 0; ksl < 4; ++ksl)
                    #pragma unroll
                    for (int j = 0; j < 4; ++j)
                        a2[r][ksl][j] = __hfma2(((const __half2*)&v[r][s][ksl])[j],
                                                m, a2[r][ksl][j]);
            }

        #pragma unroll
        for (int r = 0; r < 2; ++r) {
            p_[r] = pn[r];
            #pragma unroll
            for (int s = 0; s < 2; ++s) id[r][s] = idn[r][s];
        }
    }

    // scale to means
    half8 ag[2][4];                   // [r][ksl]
    #pragma unroll
    for (int r = 0; r < 2; ++r) {
        __half2 s2 = __float2half2_rn(inv_[r]);
        #pragma unroll
        for (int ksl = 0; ksl < 4; ++ksl) {
            half8 h;
            #pragma unroll
            for (int j = 0; j < 4; ++j)
                ((__half2*)&h)[j] = __hmul2(a2[r][ksl][j], s2);
            ag[r][ksl] = h;
        }
    }

    // ---- MFMA phase: B (and seg-0 A) direct-from-global, depth-2 prefetch ----
    auto ldB = [&](int ks, int nt) -> half8 {
        return *(const half8*)(Wp + ((size_t)(ks * 8 + nt) * 64 + lane) * 8);
    };
    const unsigned short* aBase = Xin + (size_t)(rowbase + l15) * 128 + koff;
    auto ldA = [&](int ks) -> half8 {
        return *(const half8*)(aBase + (ks & 3) * 32);
    };

    float4v acc[8];
    #pragma unroll
    for (int nt = 0; nt < 8; ++nt) {
        float bv = bias[nt * 16 + l15];
        acc[nt] = float4v{bv, bv, bv, bv};
    }

    half8 bb[2][8];                   // ping-pong, ks&1 is compile-time
    half8 ax[2];
    #pragma unroll
    for (int nt = 0; nt < 8; ++nt) bb[0][nt] = ldB(0, nt);
    ax[0] = ldA(0);

    #pragma unroll
    for (int ks = 0; ks < 12; ++ks) {
        if (ks + 1 < 12) {
            #pragma unroll
            for (int nt = 0; nt < 8; ++nt)
                bb[(ks + 1) & 1][nt] = ldB(ks + 1, nt);
            if (ks + 1 < 4) ax[(ks + 1) & 1] = ldA(ks + 1);
        }
        half8 A = (ks < 4) ? ax[ks & 1] : ag[(ks >> 2) - 1][ks & 3];
        #pragma unroll
        for (int nt = 0; nt < 8; ++nt)
            acc[nt] = __builtin_amdgcn_mfma_f32_16x16x32_f16(A, bb[ks & 1][nt], acc[nt], 0, 0, 0);
    }

    if (!FINAL) {
        // D layout: row = quad*4 + rr, col = l15 (within each 16x16 tile)
        #pragma unroll
        for (int rr = 0; rr < 4; ++rr) {
            int n2 = rowbase + quad * 4 + rr;
            unsigned short* hp = Hout + (size_t)n2 * 128 + l15;
            #pragma unroll
            for (int nt = 0; nt < 8; ++nt)
                hp[nt * 16] = f2h(fmaxf(acc[nt][rr], 0.f));
        }
    } else {
        float wc0[8], wc1[8];
        #pragma unroll
        for (int nt = 0; nt < 8; ++nt) {
            wc0[nt] = Wc[(nt * 16 + l15) * 2 + 0];
            wc1[nt] = Wc[(nt * 16 + l15) * 2 + 1];
        }
        float b0 = bc[0], b1 = bc[1];
        #pragma unroll
        for (int rr = 0; rr < 4; ++rr) {
            float l0 = 0.f, l1 = 0.f;
            #pragma unroll
            for (int nt = 0; nt < 8; ++nt) {
                float h = fmaxf(acc[nt][rr], 0.f);
                l0 += h * wc0[nt];
                l1 += h * wc1[nt];
            }
            #pragma unroll
            for (int off = 8; off > 0; off >>= 1) {
                l0 += __shfl_down(l0, off, 16);
                l1 += __shfl_down(l1, off, 16);
            }
            int n2 = rowbase + quad * 4 + rr;
            if (l15 == 0 && n2 < N_NODES) {
                Out[(size_t)n2 * 2 + 0] = l0 + b0;
                Out[(size_t)n2 * 2 + 1] = l1 + b1;
            }
        }
    }
}

extern "C" void kernel_launch(void* const* d_in, const int* in_sizes, int n_in,
                              void* d_out, int out_size, void* d_ws, size_t ws_size,
                              hipStream_t stream)
{
    const float* x      = (const float*)d_in[0];
    const int*   ei     = (const int*)d_in[1];
    const int*   et     = (const int*)d_in[2];
    const float* Wrel1  = (const float*)d_in[3];
    const float* Wroot1 = (const float*)d_in[4];
    const float* b1     = (const float*)d_in[5];
    const float* Wrel2  = (const float*)d_in[6];
    const float* Wroot2 = (const float*)d_in[7];
    const float* b2     = (const float*)d_in[8];
    const float* Wc     = (const float*)d_in[9];
    const float* bc     = (const float*)d_in[10];
    float* out = (float*)d_out;

    char* ws = (char*)d_ws;
    size_t off = 0;
    auto alloc = [&](size_t bytes) {
        void* p = ws + off;
        off += (bytes + 255) & ~(size_t)255;
        return p;
    };
    unsigned short* xb    = (unsigned short*)alloc((size_t)PAD_N * IN_DIM * 2);
    unsigned short* h1b   = (unsigned short*)alloc((size_t)PAD_N * HID * 2);
    unsigned short* Wp    = (unsigned short*)alloc((size_t)2 * 12 * 8 * 64 * 8 * 2);
    unsigned*       rs    = (unsigned*)alloc((size_t)(M_SEG + 1) * 4);
    unsigned*       cursor= (unsigned*)alloc((size_t)M_SEG * 4);   // 800000 B (256-mult)
    unsigned*       done  = (unsigned*)alloc(256);                 // adjacent to cursor
    unsigned*       bsums = (unsigned*)alloc(256 * 4);
    unsigned*       csr   = (unsigned*)alloc((size_t)N_EDGES * 4);

    const int gemm_blocks = PAD_N / 64;                 // 1564
    const int prep_blocks = CVT_BLOCKS + PACK_BLOCKS + HIST_BLOCKS;

    // ---- CSR build + conversions (graph identical for both layers) ----
    hipMemsetAsync(cursor, 0, (size_t)M_SEG * 4 + 256, stream);   // cursor + done
    prep_kernel<<<prep_blocks, 256, 0, stream>>>(
        x, xb, Wroot1, Wrel1, Wroot2, Wrel2, Wp, ei, et, cursor);
    csr_kernel<<<CSR_NB, 256, 0, stream>>>(ei, et, cursor, rs, bsums, done, csr);

    // ---- layer 1 (fused gather+gemm) ----
    gemm_kernel<false><<<gemm_blocks, 256, 0, stream>>>(
        xb, rs, csr, Wp, b1, h1b, nullptr, nullptr, nullptr);

    // ---- layer 2 (fused gather+gemm, FINAL classifier) ----
    gemm_kernel<true><<<gemm_blocks, 256, 0, stream>>>(
        h1b, rs, csr, Wp + (size_t)12 * 8 * 64 * 8, b2, nullptr, Wc, bc, out);
}

// Round 7
// 267.382 us; speedup vs baseline: 1.6030x; 1.2435x over previous
//
#include <hip/hip_runtime.h>
#include <hip/hip_fp16.h>

#define N_NODES 100000
#define PAD_N   100096                   // 782 * 128, padded M for GEMM tiles
#define IN_DIM 128
#define HID 128
#define N_REL 2
#define N_EDGES 500000
#define M_SEG (N_REL * N_NODES)          // 200000 (rel,node) segments
#define SCAN_BLK 1024
#define SCAN_NB ((M_SEG + SCAN_BLK - 1) / SCAN_BLK)   // 196

#define CVT_BLOCKS 12500                 // N_NODES*IN_DIM/4 / 256
#define PACK_BLOCKS 48                   // 2*12*8*64 / 256
#define HIST_BLOCKS 1954                 // ceil(N_EDGES/256)

#define GB_EDGES 48                      // gather batch: 48 edge-rows (12 KB/wave)

typedef __attribute__((ext_vector_type(8))) _Float16 half8;
typedef __attribute__((ext_vector_type(4))) float float4v;

__device__ __forceinline__ unsigned short f2h(float f) {
    return __half_as_ushort(__float2half(f));   // RNE
}

// ---------------------------------------------------------------------------
// Fused prep: cvt (x fp32->fp16) | pack (weights->B-frag order, fp16) | hist.
// ---------------------------------------------------------------------------
__global__ __launch_bounds__(256) void prep_kernel(
    const float* __restrict__ X, unsigned short* __restrict__ Xb,
    const float* __restrict__ Wroot1, const float* __restrict__ Wrel1,
    const float* __restrict__ Wroot2, const float* __restrict__ Wrel2,
    unsigned short* __restrict__ Wp,
    const int* __restrict__ ei, const int* __restrict__ et,
    unsigned* __restrict__ cnt)
{
    int bid = blockIdx.x;
    if (bid < CVT_BLOCKS) {
        int i = bid * 256 + threadIdx.x;
        if (i >= N_NODES * IN_DIM / 4) return;
        float4 v = ((const float4*)X)[i];
        ushort4 o;
        o.x = f2h(v.x); o.y = f2h(v.y); o.z = f2h(v.z); o.w = f2h(v.w);
        ((ushort4*)Xb)[i] = o;
    } else if (bid < CVT_BLOCKS + PACK_BLOCKS) {
        int tid = (bid - CVT_BLOCKS) * 256 + threadIdx.x;
        int layer = tid / 6144;
        int rem   = tid % 6144;
        int ks    = rem / 512;
        int rem2  = rem % 512;
        int nt    = rem2 / 64;
        int lane  = rem2 % 64;
        int seg = ks >> 2;
        int kl  = (ks & 3) * 32 + (lane >> 4) * 8;
        int chan = nt * 16 + (lane & 15);
        const float* Wroot = layer ? Wroot2 : Wroot1;
        const float* Wrel  = layer ? Wrel2  : Wrel1;
        const float* W = (seg == 0) ? Wroot : (Wrel + (size_t)(seg - 1) * 128 * 128);
        unsigned short* dst = Wp + (size_t)tid * 8;
        #pragma unroll
        for (int j = 0; j < 8; ++j)
            dst[j] = f2h(W[(size_t)(kl + j) * 128 + chan]);
    } else {
        int e = (bid - CVT_BLOCKS - PACK_BLOCKS) * 256 + threadIdx.x;
        if (e >= N_EDGES) return;
        int dst = ei[N_EDGES + e];
        int r = et[e];
        atomicAdd(cnt + (size_t)r * N_NODES + dst, 1u);
    }
}

// ---------------------------------------------------------------------------
// Scan chain for CSR row starts (scan1 -> scan3; scan2 folded into scan3)
// ---------------------------------------------------------------------------
__global__ __launch_bounds__(256) void scan1_kernel(
    const unsigned* __restrict__ cnt,
    unsigned* __restrict__ rs, unsigned* __restrict__ bsums)
{
    __shared__ unsigned sdata[256];
    int t = threadIdx.x;
    int base = blockIdx.x * SCAN_BLK + t * 4;
    unsigned v[4]; unsigned s = 0;
    #pragma unroll
    for (int j = 0; j < 4; ++j) {
        v[j] = (base + j < M_SEG) ? cnt[base + j] : 0u;
        s += v[j];
    }
    sdata[t] = s;
    __syncthreads();
    #pragma unroll
    for (int off = 1; off < 256; off <<= 1) {
        unsigned x = (t >= off) ? sdata[t - off] : 0u;
        __syncthreads();
        if (t >= off) sdata[t] += x;
        __syncthreads();
    }
    unsigned excl = (t > 0) ? sdata[t - 1] : 0u;
    if (t == 255) bsums[blockIdx.x] = sdata[255];
    unsigned run = excl;
    #pragma unroll
    for (int j = 0; j < 4; ++j) {
        if (base + j < M_SEG) rs[base + j] = run;
        run += v[j];
    }
}

// scan3: each block redundantly scans the 196 block sums in LDS (trivial),
// then applies the offset.  Removes the serial single-block scan2 dispatch.
__global__ __launch_bounds__(256) void scan3_kernel(
    unsigned* __restrict__ rs, const unsigned* __restrict__ bsums,
    unsigned* __restrict__ cursor)
{
    __shared__ unsigned sdata[256];
    int t = threadIdx.x;
    sdata[t] = (t < SCAN_NB) ? bsums[t] : 0u;
    __syncthreads();
    #pragma unroll
    for (int off = 1; off < 256; off <<= 1) {
        unsigned x = (t >= off) ? sdata[t - off] : 0u;
        __syncthreads();
        if (t >= off) sdata[t] += x;
        __syncthreads();
    }
    int i = blockIdx.x * blockDim.x + t;
    if (i < M_SEG) {
        int b = i >> 10;
        unsigned add = (b > 0) ? sdata[b - 1] : 0u;
        unsigned v = rs[i] + add;
        rs[i] = v;
        cursor[i] = v;
    }
    if (i == 0) rs[M_SEG] = N_EDGES;
}

__global__ __launch_bounds__(256) void fill_kernel(
    const int* __restrict__ ei, const int* __restrict__ et,
    unsigned* __restrict__ cursor, unsigned* __restrict__ csr)
{
    int e = blockIdx.x * blockDim.x + threadIdx.x;
    if (e >= N_EDGES) return;
    int src = ei[e];
    int dst = ei[N_EDGES + e];
    int r = et[e];
    unsigned pos = atomicAdd(cursor + (size_t)r * N_NODES + dst, 1u);
    csr[pos] = (unsigned)src;
}

// ---------------------------------------------------------------------------
// Fused gather + MFMA GEMM (fp16) with VGPR-FREE async LDS gather:
//  * Per (wave, rel) the 16 nodes' CSR segments are one contiguous edge run
//    [S,E) (~40 edges).  Up to 12 global_load_lds instructions gather
//    4 edge-rows x 16 chunks each (per-lane global addresses, linear LDS
//    dest) -> 12 KB in flight per wave with ZERO VGPR cost, then one
//    vmcnt(0) + sched_barrier, then per-lane accumulation from LDS.
//  * LDS rows are XOR-swizzled on BOTH sides (source chunk ^ (row&7) and
//    read chunk ^ (row&7)) to break the 16-way bank conflict of the
//    256 B-stride ds_read_b128 pattern.
//  * MFMA phase unchanged from round 3: B from L2 with depth-2 ping-pong,
//    256 threads, default launch bounds (forced bounds spilled in r4/r5).
// ---------------------------------------------------------------------------
template <bool FINAL>
__global__ __launch_bounds__(256) void gemm_kernel(
    const unsigned short* __restrict__ Xin,   // [PAD_N][128] fp16 (layer input + gather source)
    const unsigned* __restrict__ rs,          // [M_SEG+1] CSR row starts
    const unsigned* __restrict__ csr,         // [N_EDGES] src node per slot
    const unsigned short* __restrict__ Wp,    // packed [12][8][64][8] fp16
    const float* __restrict__ bias,           // [128] fp32
    unsigned short* __restrict__ Hout,        // [PAD_N][128] fp16 (!FINAL)
    const float* __restrict__ Wc,             // [128][2] fp32 (FINAL)
    const float* __restrict__ bc,             // [2] fp32 (FINAL)
    float* __restrict__ Out)                  // [N][2] fp32 (FINAL)
{
    __shared__ __align__(16) unsigned char gbuf[4][GB_EDGES * 256];   // 48 KB

    const int t    = threadIdx.x;
    const int w    = t >> 6;          // wave 0..3
    const int lane = t & 63;
    const int l15  = lane & 15;
    const int quad = lane >> 4;
    const int rowbase = blockIdx.x * 64 + w * 16;   // this wave's 16 nodes
    const int koff = quad * 8;
    unsigned char* myBuf = &gbuf[w][0];

    const uint4* __restrict__ X4 = (const uint4*)Xin;   // 16B units

    // ---- per-lane accumulators for the 2 relation means ----
    __half2 a2[2][4][4];              // [r][ksl][j] — statically indexed
    #pragma unroll
    for (int r = 0; r < 2; ++r)
        #pragma unroll
        for (int ksl = 0; ksl < 4; ++ksl)
            #pragma unroll
            for (int j = 0; j < 4; ++j)
                a2[r][ksl][j] = __float2half2_rn(0.f);

    const int node = rowbase + l15;
    float inv_[2] = {1.f, 1.f};

    if (rowbase < N_NODES) {          // 16-row windows are fully real or fully pad
        #pragma unroll
        for (int r = 0; r < 2; ++r) {
            // wave-uniform edge run for the window; per-lane node bounds
            unsigned S = rs[(size_t)r * N_NODES + rowbase];
            unsigned E = rs[(size_t)r * N_NODES + rowbase + 16];
            unsigned st = rs[(size_t)r * N_NODES + node];
            unsigned en = rs[(size_t)r * N_NODES + node + 1];
            unsigned d = en - st;
            inv_[r] = 1.0f / (float)(d ? d : 1u);

            for (unsigned base = S; base < E; base += GB_EDGES) {
                unsigned cnt = E - base;
                if (cnt > GB_EDGES) cnt = GB_EDGES;

                // 1) per-lane edge IDs for up to 12 gather instructions
                unsigned ids[12];
                #pragma unroll
                for (int i = 0; i < 12; ++i) {
                    if ((unsigned)(i * 4) < cnt) {
                        unsigned e = base + (unsigned)(i * 4) + (unsigned)(lane >> 4);
                        ids[i] = csr[e < E ? e : E - 1u];
                    } else ids[i] = 0u;
                }

                // 2) async gather: 4 edge-rows x 16 chunks per instruction,
                //    per-lane global source, linear LDS dest, src swizzled
                #pragma unroll
                for (int i = 0; i < 12; ++i) {
                    if ((unsigned)(i * 4) < cnt) {
                        unsigned eL = (unsigned)(i * 4) + (unsigned)(lane >> 4);
                        unsigned cg = (unsigned)(lane & 15) ^ (eL & 7u);
                        const unsigned short* gp =
                            (const unsigned short*)(X4 + ((size_t)ids[i] << 4) + cg);
                        __builtin_amdgcn_global_load_lds(
                            (const __attribute__((address_space(1))) unsigned int*)gp,
                            (__attribute__((address_space(3))) unsigned int*)(myBuf + i * 1024),
                            16, 0, 0);
                    }
                }

                asm volatile("s_waitcnt vmcnt(0)" ::: "memory");
                __builtin_amdgcn_sched_barrier(0);

                // 3) per-lane accumulation of its node's rows in this batch
                unsigned lo = st > base ? st : base;
                unsigned hiB = base + cnt;
                unsigned hi = en < hiB ? en : hiB;
                for (unsigned p = lo; p < hi; ++p) {
                    unsigned eL = p - base;
                    const unsigned char* rowb = myBuf + eL * 256;
                    #pragma unroll
                    for (int ksl = 0; ksl < 4; ++ksl) {
                        unsigned pos = ((unsigned)(ksl * 4 + quad)) ^ (eL & 7u);
                        half8 h = *(const half8*)(rowb + pos * 16);
                        #pragma unroll
                        for (int j = 0; j < 4; ++j)
                            a2[r][ksl][j] = __hadd2(a2[r][ksl][j],
                                                    ((const __half2*)&h)[j]);
                    }
                }
            }
        }
    }

    // scale to means
    half8 ag[2][4];                   // [r][ksl]
    #pragma unroll
    for (int r = 0; r < 2; ++r) {
        __half2 s2 = __float2half2_rn(inv_[r]);
        #pragma unroll
        for (int ksl = 0; ksl < 4; ++ksl) {
            half8 h;
            #pragma unroll
            for (int j = 0; j < 4; ++j)
                ((__half2*)&h)[j] = __hmul2(a2[r][ksl][j], s2);
            ag[r][ksl] = h;
        }
    }

    // ---- MFMA phase: B (and seg-0 A) direct-from-global, depth-2 prefetch ----
    auto ldB = [&](int ks, int nt) -> half8 {
        return *(const half8*)(Wp + ((size_t)(ks * 8 + nt) * 64 + lane) * 8);
    };
    const unsigned short* aBase = Xin + (size_t)(rowbase + l15) * 128 + koff;
    auto ldA = [&](int ks) -> half8 {
        return *(const half8*)(aBase + (ks & 3) * 32);
    };

    float4v acc[8];
    #pragma unroll
    for (int nt = 0; nt < 8; ++nt) {
        float bv = bias[nt * 16 + l15];
        acc[nt] = float4v{bv, bv, bv, bv};
    }

    half8 bb[2][8];                   // ping-pong, ks&1 is compile-time
    half8 ax[2];
    #pragma unroll
    for (int nt = 0; nt < 8; ++nt) bb[0][nt] = ldB(0, nt);
    ax[0] = ldA(0);

    #pragma unroll
    for (int ks = 0; ks < 12; ++ks) {
        if (ks + 1 < 12) {
            #pragma unroll
            for (int nt = 0; nt < 8; ++nt)
                bb[(ks + 1) & 1][nt] = ldB(ks + 1, nt);
            if (ks + 1 < 4) ax[(ks + 1) & 1] = ldA(ks + 1);
        }
        half8 A = (ks < 4) ? ax[ks & 1] : ag[(ks >> 2) - 1][ks & 3];
        #pragma unroll
        for (int nt = 0; nt < 8; ++nt)
            acc[nt] = __builtin_amdgcn_mfma_f32_16x16x32_f16(A, bb[ks & 1][nt], acc[nt], 0, 0, 0);
    }

    if (!FINAL) {
        // D layout: row = quad*4 + rr, col = l15 (within each 16x16 tile)
        #pragma unroll
        for (int rr = 0; rr < 4; ++rr) {
            int n2 = rowbase + quad * 4 + rr;
            unsigned short* hp = Hout + (size_t)n2 * 128 + l15;
            #pragma unroll
            for (int nt = 0; nt < 8; ++nt)
                hp[nt * 16] = f2h(fmaxf(acc[nt][rr], 0.f));
        }
    } else {
        float wc0[8], wc1[8];
        #pragma unroll
        for (int nt = 0; nt < 8; ++nt) {
            wc0[nt] = Wc[(nt * 16 + l15) * 2 + 0];
            wc1[nt] = Wc[(nt * 16 + l15) * 2 + 1];
        }
        float b0 = bc[0], b1 = bc[1];
        #pragma unroll
        for (int rr = 0; rr < 4; ++rr) {
            float l0 = 0.f, l1 = 0.f;
            #pragma unroll
            for (int nt = 0; nt < 8; ++nt) {
                float h = fmaxf(acc[nt][rr], 0.f);
                l0 += h * wc0[nt];
                l1 += h * wc1[nt];
            }
            #pragma unroll
            for (int off = 8; off > 0; off >>= 1) {
                l0 += __shfl_down(l0, off, 16);
                l1 += __shfl_down(l1, off, 16);
            }
            int n2 = rowbase + quad * 4 + rr;
            if (l15 == 0 && n2 < N_NODES) {
                Out[(size_t)n2 * 2 + 0] = l0 + b0;
                Out[(size_t)n2 * 2 + 1] = l1 + b1;
            }
        }
    }
}

extern "C" void kernel_launch(void* const* d_in, const int* in_sizes, int n_in,
                              void* d_out, int out_size, void* d_ws, size_t ws_size,
                              hipStream_t stream)
{
    const float* x      = (const float*)d_in[0];
    const int*   ei     = (const int*)d_in[1];
    const int*   et     = (const int*)d_in[2];
    const float* Wrel1  = (const float*)d_in[3];
    const float* Wroot1 = (const float*)d_in[4];
    const float* b1     = (const float*)d_in[5];
    const float* Wrel2  = (const float*)d_in[6];
    const float* Wroot2 = (const float*)d_in[7];
    const float* b2     = (const float*)d_in[8];
    const float* Wc     = (const float*)d_in[9];
    const float* bc     = (const float*)d_in[10];
    float* out = (float*)d_out;

    char* ws = (char*)d_ws;
    size_t off = 0;
    auto alloc = [&](size_t bytes) {
        void* p = ws + off;
        off += (bytes + 255) & ~(size_t)255;
        return p;
    };
    unsigned short* xb    = (unsigned short*)alloc((size_t)PAD_N * IN_DIM * 2);
    unsigned short* h1b   = (unsigned short*)alloc((size_t)PAD_N * HID * 2);
    unsigned short* Wp    = (unsigned short*)alloc((size_t)2 * 12 * 8 * 64 * 8 * 2);
    unsigned*       rs    = (unsigned*)alloc((size_t)(M_SEG + 1) * 4);
    unsigned*       cursor= (unsigned*)alloc((size_t)M_SEG * 4);
    unsigned*       bsums = (unsigned*)alloc(256 * 4);
    unsigned*       csr   = (unsigned*)alloc((size_t)N_EDGES * 4);

    const int edge_blocks = (N_EDGES + 255) / 256;
    const int seg_blocks  = (M_SEG + 255) / 256;
    const int gemm_blocks = PAD_N / 64;                 // 1564
    const int prep_blocks = CVT_BLOCKS + PACK_BLOCKS + HIST_BLOCKS;

    // ---- CSR build + conversions (graph identical for both layers) ----
    hipMemsetAsync(cursor, 0, (size_t)M_SEG * 4, stream);
    prep_kernel<<<prep_blocks, 256, 0, stream>>>(
        x, xb, Wroot1, Wrel1, Wroot2, Wrel2, Wp, ei, et, cursor);
    scan1_kernel<<<SCAN_NB, 256, 0, stream>>>(cursor, rs, bsums);
    scan3_kernel<<<seg_blocks, 256, 0, stream>>>(rs, bsums, cursor);
    fill_kernel<<<edge_blocks, 256, 0, stream>>>(ei, et, cursor, csr);

    // ---- layer 1 (fused gather+gemm) ----
    gemm_kernel<false><<<gemm_blocks, 256, 0, stream>>>(
        xb, rs, csr, Wp, b1, h1b, nullptr, nullptr, nullptr);

    // ---- layer 2 (fused gather+gemm, FINAL classifier) ----
    gemm_kernel<true><<<gemm_blocks, 256, 0, stream>>>(
        h1b, rs, csr, Wp + (size_t)12 * 8 * 64 * 8, b2, nullptr, Wc, bc, out);
}